// Round 1
// baseline (912.201 us; speedup 1.0000x reference)
//
#include <hip/hip_runtime.h>
#include <cmath>

// ---- problem dims (fixed per reference) ----
#define YCH 8        // y_channels
#define NTR 16       // trials
#define LLEN 4096    // trial length
#define CK  16       // kernels per channel
#define KS  64       // kernel size
#define ENC 4033     // LLEN - KS + 1
#define NP  128      // YCH*NTR independent problems
#define INV_LIP 0.1f     // 1/10
#define THRESH 0.01f     // LAM/LIP = 0.1/10

// =====================================================================
// Kernel A: residual  res[p,t] = y[n,ch,t] - sum_{c,k} Xt[p,c,t-k]*H[ch,c,k]
// grid (LLEN/TT, NP), 128 threads, 4 consecutive t per thread
// =====================================================================
#define TT 512
#define ATHREADS 128

__global__ __launch_bounds__(ATHREADS) void resid_kernel(
    const float* __restrict__ y, const float* __restrict__ H,
    const float* __restrict__ Xt, float* __restrict__ res)
{
    __shared__ __align__(16) float xs[CK][TT + 64];  // locals [t0-63 .. t0+TT-1+3pad]
    __shared__ __align__(16) float hs[CK][KS];
    const int tid = threadIdx.x;
    const int t0  = blockIdx.x * TT;
    const int p   = blockIdx.y;
    const int n   = p & 15;
    const int ch  = p >> 4;

    // stage H[ch]: 1024 floats
    for (int idx = tid; idx < CK * KS; idx += ATHREADS)
        hs[idx >> 6][idx & 63] = H[(size_t)ch * CK * KS + idx];

    // stage Xt tile with left halo of 63 (zero-padded outside [0,ENC))
    for (int c = 0; c < CK; ++c) {
        const float* src = Xt + (size_t)(p * CK + c) * ENC;
        for (int l = tid; l < TT + 63; l += ATHREADS) {
            int gi = t0 - 63 + l;
            xs[c][l] = (gi >= 0 && gi < ENC) ? src[gi] : 0.f;
        }
    }
    __syncthreads();

    float acc[4] = {0.f, 0.f, 0.f, 0.f};
    for (int c = 0; c < CK; ++c) {
        const float4* xr = (const float4*)(&xs[c][0]);
        const float4* hr = (const float4*)(&hs[c][0]);
        float4 cur = xr[tid];
        #pragma unroll
        for (int g = 0; g < 16; ++g) {
            float4 nxt = xr[tid + g + 1];
            float4 h4  = hr[15 - g];
            // local index = 4*tid + (63-k) + j ; kk=63-k=4g+m ; h(k)=hs[63-4g-m]=h4[3-m]
            float w[8]  = {cur.x, cur.y, cur.z, cur.w, nxt.x, nxt.y, nxt.z, nxt.w};
            float hh[4] = {h4.w, h4.z, h4.y, h4.x};
            #pragma unroll
            for (int m = 0; m < 4; ++m)
                #pragma unroll
                for (int j = 0; j < 4; ++j)
                    acc[j] = fmaf(w[m + j], hh[m], acc[j]);
            cur = nxt;
        }
    }

    const int t = t0 + 4 * tid;
    const float* yrow = y + (size_t)(n * YCH + ch) * LLEN;
    float4 yv = *(const float4*)(yrow + t);
    float4 r;
    r.x = yv.x - acc[0];
    r.y = yv.y - acc[1];
    r.z = yv.z - acc[2];
    r.w = yv.w - acc[3];
    *(float4*)(res + (size_t)p * LLEN + t) = r;
}

// =====================================================================
// Kernel B: analysis conv + FISTA update
//   g[c,i]   = sum_k rs[i+k]*H[ch,c,k]
//   x_new    = relu(x_tmp + g/LIP - LAM/LIP)
//   x_tmpNew = x_new + beta*(x_new - x_old)
// first=1: x_tmp=x_old=0 and rs comes from y (step 0, res==y)
// grid (ceil(LLEN/TI), NP), 256 threads, 4 consecutive i per thread
// =====================================================================
#define TI 1024
#define BTHREADS 256

__global__ __launch_bounds__(BTHREADS) void fista_kernel(
    const float* __restrict__ rsrc, int rsrc_is_y,
    const float* __restrict__ H,
    float* __restrict__ Xo, float* __restrict__ Xt,
    float beta, int first, int write_tmp)
{
    __shared__ __align__(16) float rs[TI + 64];
    __shared__ __align__(16) float hs[CK][KS];
    const int tid = threadIdx.x;
    const int i0  = blockIdx.x * TI;
    const int p   = blockIdx.y;
    const int n   = p & 15;
    const int ch  = p >> 4;

    for (int idx = tid; idx < CK * KS; idx += BTHREADS)
        hs[idx >> 6][idx & 63] = H[(size_t)ch * CK * KS + idx];

    const size_t roff = rsrc_is_y ? (size_t)(n * YCH + ch) * LLEN
                                  : (size_t)p * LLEN;
    for (int l = tid; l < TI + 63; l += BTHREADS) {
        int gi = i0 + l;
        rs[l] = (gi < LLEN) ? rsrc[roff + gi] : 0.f;
    }
    __syncthreads();

    const int i = i0 + 4 * tid;
    for (int c = 0; c < CK; ++c) {
        float acc[4] = {0.f, 0.f, 0.f, 0.f};
        const float4* rr = (const float4*)(&rs[0]);
        const float4* hr = (const float4*)(&hs[c][0]);
        float4 cur = rr[tid];
        #pragma unroll
        for (int g = 0; g < 16; ++g) {
            float4 nxt = rr[tid + g + 1];
            float4 h4  = hr[g];
            // local index = 4*tid + k + j ; k=4g+m ; h(k)=h4[m]
            float w[8]  = {cur.x, cur.y, cur.z, cur.w, nxt.x, nxt.y, nxt.z, nxt.w};
            float hh[4] = {h4.x, h4.y, h4.z, h4.w};
            #pragma unroll
            for (int m = 0; m < 4; ++m)
                #pragma unroll
                for (int j = 0; j < 4; ++j)
                    acc[j] = fmaf(w[m + j], hh[m], acc[j]);
            cur = nxt;
        }

        if (i < ENC) {
            const size_t idx = (size_t)(p * CK + c) * ENC + i;
            if (i + 3 < ENC) {
                // fast vector path
                float4 xt4 = first ? make_float4(0,0,0,0) : *(const float4*)(Xt + idx);
                float4 xo4 = first ? make_float4(0,0,0,0) : *(const float4*)(Xo + idx);
                float xt[4] = {xt4.x, xt4.y, xt4.z, xt4.w};
                float xo[4] = {xo4.x, xo4.y, xo4.z, xo4.w};
                float xn[4], xp[4];
                #pragma unroll
                for (int j = 0; j < 4; ++j) {
                    xn[j] = fmaxf(xt[j] + acc[j] * INV_LIP - THRESH, 0.f);
                    xp[j] = xn[j] + beta * (xn[j] - xo[j]);
                }
                *(float4*)(Xo + idx) = make_float4(xn[0], xn[1], xn[2], xn[3]);
                if (write_tmp)
                    *(float4*)(Xt + idx) = make_float4(xp[0], xp[1], xp[2], xp[3]);
            } else {
                #pragma unroll
                for (int j = 0; j < 4; ++j) {
                    if (i + j < ENC) {
                        float xt = first ? 0.f : Xt[idx + j];
                        float xo = first ? 0.f : Xo[idx + j];
                        float xn = fmaxf(xt + acc[j] * INV_LIP - THRESH, 0.f);
                        Xo[idx + j] = xn;
                        if (write_tmp) Xt[idx + j] = xn + beta * (xn - xo);
                    }
                }
            }
        }
    }
}

// =====================================================================
extern "C" void kernel_launch(void* const* d_in, const int* in_sizes, int n_in,
                              void* d_out, int out_size, void* d_ws, size_t ws_size,
                              hipStream_t stream) {
    const float* y = (const float*)d_in[0];   // [NTR, YCH, LLEN]
    const float* H = (const float*)d_in[1];   // [YCH, CK, 1, KS]
    float* Xo  = (float*)d_out;               // x_old / x_new  [p, c, i]
    float* Xt  = (float*)d_ws;                // x_tmp          [p, c, i]
    float* res = (float*)((char*)d_ws + (size_t)NP * CK * ENC * sizeof(float));

    dim3 gA(LLEN / TT, NP), bA(ATHREADS);
    dim3 gB((LLEN + TI - 1) / TI, NP), bB(BTHREADS);

    float s = 1.f;
    for (int step = 0; step < 10; ++step) {
        float s_new = 0.5f * (1.f + sqrtf(1.f + 4.f * s * s));
        float beta  = (s - 1.f) / s_new;   // 0 at step 0
        s = s_new;
        if (step == 0) {
            // x_tmp = 0  =>  res = y ; fuse into the update kernel
            fista_kernel<<<gB, bB, 0, stream>>>(y, 1, H, Xo, Xt, beta, 1, 1);
        } else {
            resid_kernel<<<gA, bA, 0, stream>>>(y, H, Xt, res);
            fista_kernel<<<gB, bB, 0, stream>>>(res, 0, H, Xo, Xt, beta, 0,
                                                (step < 9) ? 1 : 0);
        }
    }
}